// Round 3
// baseline (324.969 us; speedup 1.0000x reference)
//
#include <hip/hip_runtime.h>

typedef __attribute__((ext_vector_type(8))) __bf16 bf16x8;
typedef __attribute__((ext_vector_type(8))) unsigned short u16x8;
typedef __attribute__((ext_vector_type(4))) float f32x4;

#define N_LOCI   59412
#define T_DIM    500
#define T_PAD    512
#define N_ENC    200
#define KL       29696
#define KR       29716
#define J_STATS  59456   // loci padded to 64
#define G1_S     58      // split-K chunks per compartment (58*512 = 29696)

__device__ __forceinline__ unsigned short cvt1(float x) {
    __bf16 h = (__bf16)x;                       // RNE, compiler emits v_cvt_pk_bf16_f32 pairs
    return __builtin_bit_cast(unsigned short, h);
}
__device__ __forceinline__ f32x4 mfma16(u16x8 a, u16x8 b, f32x4 c) {
    return __builtin_amdgcn_mfma_f32_16x16x32_bf16(
        __builtin_bit_cast(bf16x8, a), __builtin_bit_cast(bf16x8, b), c, 0, 0, 0);
}

// ---------------------------------------------------------------------------
// K0: per-locus stats of X: mu[row], inv[row] = 1/||x - mu||. Pad rows -> 0.
// One wave per row.
// ---------------------------------------------------------------------------
__global__ __launch_bounds__(256) void k0_stats(const float* __restrict__ X,
                                                float* __restrict__ mu,
                                                float* __restrict__ inv) {
    const int row  = blockIdx.x * 4 + (threadIdx.x >> 6);
    const int lane = threadIdx.x & 63;
    if (row >= N_LOCI) {
        if (lane == 0 && row < J_STATS) { mu[row] = 0.0f; inv[row] = 0.0f; }
        return;
    }
    const float4* xr = (const float4*)(X + (size_t)row * T_DIM);
    float4 v1 = xr[lane];
    float4 v2 = make_float4(0.f, 0.f, 0.f, 0.f);
    if ((lane + 64) < 125) v2 = xr[lane + 64];
    float s = v1.x + v1.y + v1.z + v1.w + v2.x + v2.y + v2.z + v2.w;
    float q = v1.x * v1.x + v1.y * v1.y + v1.z * v1.z + v1.w * v1.w
            + v2.x * v2.x + v2.y * v2.y + v2.z * v2.z + v2.w * v2.w;
    #pragma unroll
    for (int off = 32; off; off >>= 1) {
        s += __shfl_xor(s, off);
        q += __shfl_xor(q, off);
    }
    if (lane == 0) {
        const float mean = s * (1.0f / 500.0f);
        mu[row]  = mean;
        inv[row] = rsqrtf(q - 500.0f * mean * mean);
    }
}

// ---------------------------------------------------------------------------
// K2: references partials = W_c @ X_slice (raw f32 -> bf16 in-kernel).
//     Tile 128m x 64n, BK=64, 4 waves (2m x 2n, each 64x32).
//     Grid (16 = 8 ntile | 2 mtile, 58 split-K, 2 comps) = 1856 blocks.
//     Partials -> P[(comp*58+s)][200][512] f32.
// ---------------------------------------------------------------------------
__global__ __launch_bounds__(256, 4) void k2_gemm1(const float* __restrict__ X,
                                                   const float* __restrict__ WL,
                                                   const float* __restrict__ WR,
                                                   float* __restrict__ P) {
    const int nt   = blockIdx.x >> 1;   // 0..7
    const int mt   = blockIdx.x & 1;    // 0..1
    const int sc   = blockIdx.y;        // 0..57
    const int comp = blockIdx.z;        // 0..1
    const int K       = comp ? KR : KL;
    const float* W    = comp ? WR : WL;
    const int xbase   = comp ? KL : 0;
    const int n0 = nt * 64;
    const int m0 = mt * 128;

    __shared__ unsigned short As[128 * 72];   // [m][k], stride 72 (144B, 16B-mult)
    __shared__ unsigned short Bs[64 * 72];    // [n][k], stride 72

    const int t = threadIdx.x, lane = t & 63, wid = t >> 6;
    const int wm = wid >> 1, wn = wid & 1;

    f32x4 acc[4][2];
    #pragma unroll
    for (int i = 0; i < 4; ++i)
        #pragma unroll
        for (int j = 0; j < 2; ++j) {
            f32x4 z = {0.f, 0.f, 0.f, 0.f};
            acc[i][j] = z;
        }

    const int nsteps = 8 + ((comp == 1 && sc == 57) ? 1 : 0);

    // A staging map: row am (0..127), k-half aseg (32 k each)
    const int am = t >> 1, aseg = t & 1;
    const int arow = m0 + am;
    const bool arow_ok = arow < N_ENC;
    const float* wrow = W + (size_t)arow * K;
    // B staging map: k-row bk (0..63), col group bh (16 cols each)
    const int bk = t >> 2, bh = t & 3;

    for (int st = 0; st < nsteps; ++st) {
        const int k0 = sc * 512 + st * 64;
        // ---- stage A = W[128 x 64] -> bf16 ----
        {
            const int kb = k0 + aseg * 32;
            if (arow_ok && (kb + 32 <= K)) {
                #pragma unroll
                for (int s2 = 0; s2 < 4; ++s2) {
                    const float4 p = *(const float4*)(wrow + kb + 8 * s2);
                    const float4 r = *(const float4*)(wrow + kb + 8 * s2 + 4);
                    u16x8 h;
                    h[0] = cvt1(p.x); h[1] = cvt1(p.y); h[2] = cvt1(p.z); h[3] = cvt1(p.w);
                    h[4] = cvt1(r.x); h[5] = cvt1(r.y); h[6] = cvt1(r.z); h[7] = cvt1(r.w);
                    *(u16x8*)&As[am * 72 + aseg * 32 + 8 * s2] = h;
                }
            } else {
                #pragma unroll
                for (int s2 = 0; s2 < 4; ++s2) {
                    u16x8 h;
                    #pragma unroll
                    for (int j = 0; j < 8; ++j) {
                        const int kk = kb + 8 * s2 + j;
                        h[j] = cvt1((arow_ok && kk < K) ? wrow[kk] : 0.0f);
                    }
                    *(u16x8*)&As[am * 72 + aseg * 32 + 8 * s2] = h;
                }
            }
        }
        // ---- stage B = X[64 x 64] transposed -> [n][k] ----
        {
            const int krel = k0 + bk;
            const bool kok = krel < K;
            const float* xr = X + (size_t)(xbase + krel) * T_DIM;
            #pragma unroll
            for (int q = 0; q < 4; ++q) {
                const int c = n0 + bh * 16 + q * 4;
                float4 xv = make_float4(0.f, 0.f, 0.f, 0.f);
                if (kok) {
                    if (c + 4 <= T_DIM) {
                        xv = *(const float4*)(xr + c);
                    } else {
                        xv.x = (c + 0 < T_DIM) ? xr[c + 0] : 0.0f;
                        xv.y = (c + 1 < T_DIM) ? xr[c + 1] : 0.0f;
                        xv.z = (c + 2 < T_DIM) ? xr[c + 2] : 0.0f;
                        xv.w = (c + 3 < T_DIM) ? xr[c + 3] : 0.0f;
                    }
                }
                const int nb = bh * 16 + q * 4;
                Bs[(nb + 0) * 72 + bk] = cvt1(xv.x);
                Bs[(nb + 1) * 72 + bk] = cvt1(xv.y);
                Bs[(nb + 2) * 72 + bk] = cvt1(xv.z);
                Bs[(nb + 3) * 72 + bk] = cvt1(xv.w);
            }
        }
        __syncthreads();
        // ---- MFMA over two 32-k halves ----
        #pragma unroll
        for (int half = 0; half < 2; ++half) {
            u16x8 af[4], bg[2];
            #pragma unroll
            for (int mf = 0; mf < 4; ++mf)
                af[mf] = *(const u16x8*)&As[(wm * 64 + mf * 16 + (lane & 15)) * 72
                                            + half * 32 + (lane >> 4) * 8];
            #pragma unroll
            for (int nf = 0; nf < 2; ++nf)
                bg[nf] = *(const u16x8*)&Bs[(wn * 32 + nf * 16 + (lane & 15)) * 72
                                            + half * 32 + (lane >> 4) * 8];
            #pragma unroll
            for (int mf = 0; mf < 4; ++mf)
                #pragma unroll
                for (int nf = 0; nf < 2; ++nf)
                    acc[mf][nf] = mfma16(af[mf], bg[nf], acc[mf][nf]);
        }
        __syncthreads();
    }

    float* Pb = P + (size_t)(comp * G1_S + sc) * (200 * 512);
    #pragma unroll
    for (int mf = 0; mf < 4; ++mf)
        #pragma unroll
        for (int nf = 0; nf < 2; ++nf)
            #pragma unroll
            for (int r = 0; r < 4; ++r) {
                const int m = m0 + wm * 64 + mf * 16 + (lane >> 4) * 4 + r;
                const int n = n0 + wn * 32 + nf * 16 + (lane & 15);
                if (m < N_ENC)
                    Pb[(size_t)m * 512 + n] = acc[mf][nf][r];
            }
}

// ---------------------------------------------------------------------------
// K3: sum split-K partials, center+normalize reference rows -> A_hat bf16
//     [512][512] (rows >= 400 and cols >= 500 zeroed).
// ---------------------------------------------------------------------------
__global__ __launch_bounds__(256) void k3_astats(const float* __restrict__ P,
                                                 unsigned short* __restrict__ Ah) {
    const int r = blockIdx.x;   // 0..511
    const int t = threadIdx.x;  // 0..255
    unsigned short* out = Ah + (size_t)r * T_PAD;
    if (r >= 2 * N_ENC) { out[t] = 0; out[t + 256] = 0; return; }
    const int comp = (r >= N_ENC) ? 1 : 0;
    const int m = r - comp * N_ENC;
    float a1 = 0.0f, a2 = 0.0f;
    for (int s2 = 0; s2 < G1_S; ++s2) {
        const float* Pb = P + ((size_t)(comp * G1_S + s2) * 200 + m) * 512;
        a1 += Pb[t];
        a2 += Pb[t + 256];
    }
    const bool v2ok = (t + 256) < T_DIM;
    const float b2 = v2ok ? a2 : 0.0f;
    float s = a1 + b2;
    float q = a1 * a1 + b2 * b2;
    #pragma unroll
    for (int off = 32; off; off >>= 1) {
        s += __shfl_xor(s, off);
        q += __shfl_xor(q, off);
    }
    __shared__ float ls[4], lq[4];
    if ((t & 63) == 0) { ls[t >> 6] = s; lq[t >> 6] = q; }
    __syncthreads();
    const float S = ls[0] + ls[1] + ls[2] + ls[3];
    const float Q = lq[0] + lq[1] + lq[2] + lq[3];
    const float mean = S * (1.0f / 500.0f);
    const float iv   = rsqrtf(Q - 500.0f * mean * mean);
    out[t] = cvt1((a1 - mean) * iv);
    out[t + 256] = v2ok ? cvt1((a2 - mean) * iv) : (unsigned short)0;
}

// ---------------------------------------------------------------------------
// K4: C[400 x 59412] = A_hat @ X_hat^T, X_hat computed on the fly from raw X
//     + stats. Tile 256m x 64j, 4 waves (4m x 1j, each 64x64), 16 k-steps.
// ---------------------------------------------------------------------------
__global__ __launch_bounds__(256, 3) void k4_gemm2(const unsigned short* __restrict__ Ah,
                                                   const float* __restrict__ X,
                                                   const float* __restrict__ mu,
                                                   const float* __restrict__ inv,
                                                   float* __restrict__ C) {
    const int j0 = blockIdx.x * 64;
    const int m0 = blockIdx.y * 256;

    __shared__ unsigned short As[256 * 40];   // [m][k], stride 40 (80B)
    __shared__ unsigned short Bs[64 * 40];    // [j][k], stride 40

    const int t = threadIdx.x, lane = t & 63, wm = t >> 6;

    f32x4 acc[4][4];
    #pragma unroll
    for (int i = 0; i < 4; ++i)
        #pragma unroll
        for (int j = 0; j < 4; ++j) {
            f32x4 z = {0.f, 0.f, 0.f, 0.f};
            acc[i][j] = z;
        }

    const unsigned short* arow = Ah + (size_t)(m0 + t) * T_PAD;
    const int bj = t >> 2, bh = t & 3;
    const int gj = j0 + bj;
    const bool jok = gj < N_LOCI;
    const float* xr = X + (size_t)(jok ? gj : 0) * T_DIM;
    const float bmu  = jok ? mu[gj]  : 0.0f;
    const float binv = jok ? inv[gj] : 0.0f;

    for (int st = 0; st < 16; ++st) {
        const int k0 = st * 32;
        // global loads first
        u16x8 a0 = *(const u16x8*)(arow + k0);
        u16x8 a1 = *(const u16x8*)(arow + k0 + 8);
        u16x8 a2 = *(const u16x8*)(arow + k0 + 16);
        u16x8 a3 = *(const u16x8*)(arow + k0 + 24);
        float xv[8];
        #pragma unroll
        for (int i = 0; i < 8; ++i) {
            const int c = k0 + bh * 8 + i;
            xv[i] = (jok && c < T_DIM) ? xr[c] : 0.0f;
        }
        __syncthreads();
        *(u16x8*)&As[t * 40 + 0]  = a0;
        *(u16x8*)&As[t * 40 + 8]  = a1;
        *(u16x8*)&As[t * 40 + 16] = a2;
        *(u16x8*)&As[t * 40 + 24] = a3;
        {
            u16x8 h;
            #pragma unroll
            for (int i = 0; i < 8; ++i) {
                const int c = k0 + bh * 8 + i;
                const float v = (jok && c < T_DIM) ? (xv[i] - bmu) * binv : 0.0f;
                h[i] = cvt1(v);
            }
            *(u16x8*)&Bs[bj * 40 + bh * 8] = h;
        }
        __syncthreads();
        u16x8 af[4], bg[4];
        #pragma unroll
        for (int mf = 0; mf < 4; ++mf)
            af[mf] = *(const u16x8*)&As[(wm * 64 + mf * 16 + (lane & 15)) * 40 + (lane >> 4) * 8];
        #pragma unroll
        for (int nf = 0; nf < 4; ++nf)
            bg[nf] = *(const u16x8*)&Bs[(nf * 16 + (lane & 15)) * 40 + (lane >> 4) * 8];
        #pragma unroll
        for (int mf = 0; mf < 4; ++mf)
            #pragma unroll
            for (int nf = 0; nf < 4; ++nf)
                acc[mf][nf] = mfma16(af[mf], bg[nf], acc[mf][nf]);
    }

    #pragma unroll
    for (int mf = 0; mf < 4; ++mf) {
        const int row = m0 + wm * 64 + mf * 16 + (lane >> 4) * 4;
        #pragma unroll
        for (int nf = 0; nf < 4; ++nf) {
            const int col = j0 + nf * 16 + (lane & 15);
            if (col < N_LOCI) {
                #pragma unroll
                for (int rr = 0; rr < 4; ++rr) {
                    if (row + rr < 2 * N_ENC)
                        C[(size_t)(row + rr) * N_LOCI + col] = acc[mf][nf][rr];
                }
            }
        }
    }
}

// ---------------------------------------------------------------------------
extern "C" void kernel_launch(void* const* d_in, const int* in_sizes, int n_in,
                              void* d_out, int out_size, void* d_ws, size_t ws_size,
                              hipStream_t stream) {
    const float* X  = (const float*)d_in[0];
    const float* WL = (const float*)d_in[1];
    const float* WR = (const float*)d_in[2];
    float* C = (float*)d_out;

    // workspace layout (total ~48.5 MB):
    //   mu  f32 [59456]               :   237,824 B
    //   inv f32 [59456]               :   237,824 B
    //   P   f32 [116][200][512]       : 47,513,600 B
    //   Ah  u16 [512][512]            :    524,288 B
    char* w = (char*)d_ws;
    float* mu  = (float*)w;                       w += (size_t)J_STATS * 4;
    float* inv = (float*)w;                       w += (size_t)J_STATS * 4;
    float* P   = (float*)w;                       w += (size_t)2 * G1_S * 200 * 512 * 4;
    unsigned short* Ah = (unsigned short*)w;

    k0_stats<<<dim3(J_STATS / 4), dim3(256), 0, stream>>>(X, mu, inv);
    k2_gemm1<<<dim3(16, G1_S, 2), dim3(256), 0, stream>>>(X, WL, WR, P);
    k3_astats<<<dim3(512), dim3(256), 0, stream>>>(P, Ah);
    k4_gemm2<<<dim3((N_LOCI + 63) / 64, 2), dim3(256), 0, stream>>>(Ah, X, mu, inv, C);
}

// Round 4
// 229.168 us; speedup vs baseline: 1.4180x; 1.4180x over previous
//
#include <hip/hip_runtime.h>

typedef __attribute__((ext_vector_type(8))) __bf16 bf16x8;
typedef __attribute__((ext_vector_type(8))) unsigned short u16x8;
typedef __attribute__((ext_vector_type(4))) unsigned short u16x4;
typedef __attribute__((ext_vector_type(4))) float f32x4;

#define N_LOCI   59412
#define T_DIM    500
#define T_PAD    512
#define N_ENC    200
#define KL       29696
#define KR       29716
#define J_PAD    59648   // 466 * 128
#define G1_S     58      // split-K chunks per compartment (58*512 = 29696)

__device__ __forceinline__ unsigned short cvt1(float x) {
    __bf16 h = (__bf16)x;   // RNE; compiler packs into v_cvt_pk_bf16_f32
    return __builtin_bit_cast(unsigned short, h);
}
__device__ __forceinline__ f32x4 mfma16(u16x8 a, u16x8 b, f32x4 c) {
    return __builtin_amdgcn_mfma_f32_16x16x32_bf16(
        __builtin_bit_cast(bf16x8, a), __builtin_bit_cast(bf16x8, b), c, 0, 0, 0);
}

// ---------------------------------------------------------------------------
// K0: per-row mean/norm of X; write normalized-centered bf16 X_hat
//     padded to [59648][512] with zeros. One wave per row.
// ---------------------------------------------------------------------------
__global__ __launch_bounds__(256) void k0_xnorm(const float* __restrict__ X,
                                                unsigned short* __restrict__ Xh) {
    const int row  = blockIdx.x * 4 + (threadIdx.x >> 6);
    const int lane = threadIdx.x & 63;
    unsigned short* out = Xh + (size_t)row * T_PAD;
    if (row >= N_LOCI) {
        u16x4 z = {0, 0, 0, 0};
        *(u16x4*)(out + lane * 4) = z;
        *(u16x4*)(out + (lane + 64) * 4) = z;
        return;
    }
    const float4* xr = (const float4*)(X + (size_t)row * T_DIM);
    float4 v1 = xr[lane];
    float4 v2 = make_float4(0.f, 0.f, 0.f, 0.f);
    const bool has2 = (lane + 64) < 125;
    if (has2) v2 = xr[lane + 64];
    float s = v1.x + v1.y + v1.z + v1.w + v2.x + v2.y + v2.z + v2.w;
    float q = v1.x * v1.x + v1.y * v1.y + v1.z * v1.z + v1.w * v1.w
            + v2.x * v2.x + v2.y * v2.y + v2.z * v2.z + v2.w * v2.w;
    #pragma unroll
    for (int off = 32; off; off >>= 1) {
        s += __shfl_xor(s, off);
        q += __shfl_xor(q, off);
    }
    const float mean = s * (1.0f / 500.0f);
    const float inv  = rsqrtf(q - 500.0f * mean * mean);
    u16x4 w1, w2 = {0, 0, 0, 0};
    w1[0] = cvt1((v1.x - mean) * inv);
    w1[1] = cvt1((v1.y - mean) * inv);
    w1[2] = cvt1((v1.z - mean) * inv);
    w1[3] = cvt1((v1.w - mean) * inv);
    if (has2) {
        w2[0] = cvt1((v2.x - mean) * inv);
        w2[1] = cvt1((v2.y - mean) * inv);
        w2[2] = cvt1((v2.z - mean) * inv);
        w2[3] = cvt1((v2.w - mean) * inv);
    }
    *(u16x4*)(out + lane * 4) = w1;
    *(u16x4*)(out + (lane + 64) * 4) = w2;
}

// ---------------------------------------------------------------------------
// K2: reference partials = W_c @ X_slice. Tile 128m x 128n, BK=64, 4 waves
//     (2x2, wave-tile 64x64). XOR-swizzled LDS (stride 64 shorts,
//     key = ((row>>2)&7)<<3) -> conflict-free b64/b128 writes and b128 reads.
//     Software prefetch: next step's global loads issued during MFMA phase.
//     Grid (8 = 4nt|2mt, 58 sc, 2 comp) = 928 blocks.
// ---------------------------------------------------------------------------
__global__ __launch_bounds__(256, 3) void k2_gemm1(const float* __restrict__ X,
                                                   const float* __restrict__ WL,
                                                   const float* __restrict__ WR,
                                                   float* __restrict__ P) {
    const int nt   = blockIdx.x & 3;
    const int mt   = blockIdx.x >> 2;
    const int sc   = blockIdx.y;
    const int comp = blockIdx.z;
    const int K      = comp ? KR : KL;
    const float* W   = comp ? WR : WL;
    const int xbase  = comp ? KL : 0;
    const int n0 = nt * 128, m0 = mt * 128;

    __shared__ unsigned short As[128 * 64];
    __shared__ unsigned short Bs[128 * 64];

    const int t = threadIdx.x, lane = t & 63;
    const int wm = (t >> 6) >> 1, wn = (t >> 6) & 1;
    const int lg = lane >> 4, lr = lane & 15;

    f32x4 acc[4][4];
    #pragma unroll
    for (int i = 0; i < 4; ++i)
        #pragma unroll
        for (int j = 0; j < 4; ++j) {
            f32x4 z = {0.f, 0.f, 0.f, 0.f};
            acc[i][j] = z;
        }

    const int nsteps = (comp && sc == 57) ? 9 : 8;

    // A staging: row am (0..127), 32-k seg. Rows >=200 clamped (garbage OK:
    // P write guarded m<200).
    const int am = t >> 1, aseg = t & 1;
    const int arow = (m0 + am < N_ENC) ? (m0 + am) : (N_ENC - 1);
    const float* wrow = W + (size_t)arow * K;
    const int akey = ((am >> 2) & 7) << 3;
    // B staging: thread owns k-quad kq (4 rows) x col-group tc (8 cols)
    const int kq = t >> 4, tc = t & 15;

    u16x8 ha[4];
    u16x4 hb[8];

    auto load_tiles = [&](int st, u16x8 (&la)[4], u16x4 (&lb)[8]) {
        const int k0 = sc * 512 + st * 64;
        const int kb = k0 + aseg * 32;
        if (kb + 32 <= K) {
            #pragma unroll
            for (int q = 0; q < 4; ++q) {
                const float4 v0 = *(const float4*)(wrow + kb + q * 8);
                const float4 v1 = *(const float4*)(wrow + kb + q * 8 + 4);
                u16x8 h;
                h[0] = cvt1(v0.x); h[1] = cvt1(v0.y); h[2] = cvt1(v0.z); h[3] = cvt1(v0.w);
                h[4] = cvt1(v1.x); h[5] = cvt1(v1.y); h[6] = cvt1(v1.z); h[7] = cvt1(v1.w);
                la[q] = h;
            }
        } else {
            #pragma unroll
            for (int q = 0; q < 4; ++q) {
                u16x8 h;
                #pragma unroll
                for (int j2 = 0; j2 < 8; ++j2) {
                    const int kk = kb + q * 8 + j2;
                    h[j2] = cvt1(kk < K ? wrow[kk] : 0.0f);
                }
                la[q] = h;
            }
        }
        unsigned short tmp[4][8];
        #pragma unroll
        for (int r = 0; r < 4; ++r) {
            const int krel = k0 + kq * 4 + r;
            if (krel < K) {
                const float* xr = X + (size_t)(xbase + krel) * T_DIM;
                const int c0  = n0 + tc * 8;
                const int ca0 = (c0 < 496) ? c0 : 496;        // clamp keeps loads
                const int ca1 = (c0 + 4 < 496) ? c0 + 4 : 496; // in-bounds; cols>=500 unused
                const float4 v0 = *(const float4*)(xr + ca0);
                const float4 v1 = *(const float4*)(xr + ca1);
                tmp[r][0] = cvt1(v0.x); tmp[r][1] = cvt1(v0.y);
                tmp[r][2] = cvt1(v0.z); tmp[r][3] = cvt1(v0.w);
                tmp[r][4] = cvt1(v1.x); tmp[r][5] = cvt1(v1.y);
                tmp[r][6] = cvt1(v1.z); tmp[r][7] = cvt1(v1.w);
            } else {
                #pragma unroll
                for (int j2 = 0; j2 < 8; ++j2) tmp[r][j2] = 0;
            }
        }
        #pragma unroll
        for (int j2 = 0; j2 < 8; ++j2) {
            u16x4 w4 = { tmp[0][j2], tmp[1][j2], tmp[2][j2], tmp[3][j2] };
            lb[j2] = w4;
        }
    };

    load_tiles(0, ha, hb);

    for (int st = 0; st < nsteps; ++st) {
        #pragma unroll
        for (int q = 0; q < 4; ++q)
            *(u16x8*)&As[am * 64 + ((aseg * 32 + q * 8) ^ akey)] = ha[q];
        #pragma unroll
        for (int j2 = 0; j2 < 8; ++j2) {
            const int tcol = tc * 8 + j2;
            *(u16x4*)&Bs[tcol * 64 + ((kq * 4) ^ (((tcol >> 2) & 7) << 3))] = hb[j2];
        }
        __syncthreads();
        u16x8 na[4]; u16x4 nb[8];
        const bool more = (st + 1) < nsteps;
        if (more) load_tiles(st + 1, na, nb);
        #pragma unroll
        for (int h = 0; h < 2; ++h) {
            u16x8 bf4[4];
            #pragma unroll
            for (int nf = 0; nf < 4; ++nf) {
                const int n = wn * 64 + nf * 16 + lr;
                bf4[nf] = *(const u16x8*)&Bs[n * 64 + ((h * 32 + lg * 8) ^ (((n >> 2) & 7) << 3))];
            }
            #pragma unroll
            for (int mf = 0; mf < 4; ++mf) {
                const int m = wm * 64 + mf * 16 + lr;
                const u16x8 af = *(const u16x8*)&As[m * 64 + ((h * 32 + lg * 8) ^ (((m >> 2) & 7) << 3))];
                #pragma unroll
                for (int nf = 0; nf < 4; ++nf)
                    acc[mf][nf] = mfma16(af, bf4[nf], acc[mf][nf]);
            }
        }
        __syncthreads();
        if (more) {
            #pragma unroll
            for (int q = 0; q < 4; ++q) ha[q] = na[q];
            #pragma unroll
            for (int j2 = 0; j2 < 8; ++j2) hb[j2] = nb[j2];
        }
    }

    float* Pb = P + (size_t)(comp * G1_S + sc) * (200 * 512);
    #pragma unroll
    for (int mf = 0; mf < 4; ++mf)
        #pragma unroll
        for (int nf = 0; nf < 4; ++nf)
            #pragma unroll
            for (int rr = 0; rr < 4; ++rr) {
                const int m = m0 + wm * 64 + mf * 16 + lg * 4 + rr;
                const int n = n0 + wn * 64 + nf * 16 + lr;
                if (m < N_ENC)
                    Pb[(size_t)m * 512 + n] = acc[mf][nf][rr];
            }
}

// ---------------------------------------------------------------------------
// K3: sum split-K partials, center+normalize reference rows -> A_hat bf16
//     [512][512] (rows >= 400 and cols >= 500 zeroed).
// ---------------------------------------------------------------------------
__global__ __launch_bounds__(256) void k3_astats(const float* __restrict__ P,
                                                 unsigned short* __restrict__ Ah) {
    const int r = blockIdx.x;
    const int t = threadIdx.x;
    unsigned short* out = Ah + (size_t)r * T_PAD;
    if (r >= 2 * N_ENC) { out[t] = 0; out[t + 256] = 0; return; }
    const int comp = (r >= N_ENC) ? 1 : 0;
    const int m = r - comp * N_ENC;
    float a1 = 0.0f, a2 = 0.0f;
    for (int s2 = 0; s2 < G1_S; ++s2) {
        const float* Pb = P + ((size_t)(comp * G1_S + s2) * 200 + m) * 512;
        a1 += Pb[t];
        a2 += Pb[t + 256];
    }
    const bool v2ok = (t + 256) < T_DIM;
    const float b2 = v2ok ? a2 : 0.0f;
    float s = a1 + b2;
    float q = a1 * a1 + b2 * b2;
    #pragma unroll
    for (int off = 32; off; off >>= 1) {
        s += __shfl_xor(s, off);
        q += __shfl_xor(q, off);
    }
    __shared__ float ls[4], lq[4];
    if ((t & 63) == 0) { ls[t >> 6] = s; lq[t >> 6] = q; }
    __syncthreads();
    const float S = ls[0] + ls[1] + ls[2] + ls[3];
    const float Q = lq[0] + lq[1] + lq[2] + lq[3];
    const float mean = S * (1.0f / 500.0f);
    const float iv   = rsqrtf(Q - 500.0f * mean * mean);
    out[t] = cvt1((a1 - mean) * iv);
    out[t + 256] = v2ok ? cvt1((a2 - mean) * iv) : (unsigned short)0;
}

// ---------------------------------------------------------------------------
// K4: C[400 x 59412] = A_hat @ X_hat^T. Tile 128m x 128j, BK=64, 4 waves
//     (2x2, wave 64x64). Same swizzled LDS + prefetch as K2; pure bf16 copy
//     staging (u16x8 loads). Grid (465, 4).
// ---------------------------------------------------------------------------
__global__ __launch_bounds__(256, 3) void k4_gemm2(const unsigned short* __restrict__ Ahat,
                                                   const unsigned short* __restrict__ Xh,
                                                   float* __restrict__ C) {
    const int j0 = blockIdx.x * 128;
    const int m0 = blockIdx.y * 128;
    __shared__ unsigned short As[128 * 64];
    __shared__ unsigned short Bs[128 * 64];
    const int t = threadIdx.x, lane = t & 63;
    const int wm = (t >> 6) >> 1, wn = (t >> 6) & 1;
    const int lg = lane >> 4, lr = lane & 15;

    f32x4 acc[4][4];
    #pragma unroll
    for (int i = 0; i < 4; ++i)
        #pragma unroll
        for (int j = 0; j < 4; ++j) {
            f32x4 z = {0.f, 0.f, 0.f, 0.f};
            acc[i][j] = z;
        }

    const int ar = t >> 1, aseg = t & 1;
    const unsigned short* ag = Ahat + (size_t)(m0 + ar) * T_PAD + aseg * 32;
    const unsigned short* bg = Xh   + (size_t)(j0 + ar) * T_PAD + aseg * 32;
    const int akey = ((ar >> 2) & 7) << 3;

    u16x8 ha[4], hb[4];
    auto load4 = [&](int k0, u16x8 (&la)[4], u16x8 (&lb)[4]) {
        #pragma unroll
        for (int q = 0; q < 4; ++q) la[q] = *(const u16x8*)(ag + k0 + q * 8);
        #pragma unroll
        for (int q = 0; q < 4; ++q) lb[q] = *(const u16x8*)(bg + k0 + q * 8);
    };
    load4(0, ha, hb);

    for (int st = 0; st < 8; ++st) {
        #pragma unroll
        for (int q = 0; q < 4; ++q) {
            const int off = ar * 64 + ((aseg * 32 + q * 8) ^ akey);
            *(u16x8*)&As[off] = ha[q];
            *(u16x8*)&Bs[off] = hb[q];
        }
        __syncthreads();
        u16x8 na[4], nb[4];
        const bool more = st < 7;
        if (more) load4((st + 1) * 64, na, nb);
        #pragma unroll
        for (int h = 0; h < 2; ++h) {
            u16x8 bf4[4];
            #pragma unroll
            for (int nf = 0; nf < 4; ++nf) {
                const int n = wn * 64 + nf * 16 + lr;
                bf4[nf] = *(const u16x8*)&Bs[n * 64 + ((h * 32 + lg * 8) ^ (((n >> 2) & 7) << 3))];
            }
            #pragma unroll
            for (int mf = 0; mf < 4; ++mf) {
                const int m = wm * 64 + mf * 16 + lr;
                const u16x8 af = *(const u16x8*)&As[m * 64 + ((h * 32 + lg * 8) ^ (((m >> 2) & 7) << 3))];
                #pragma unroll
                for (int nf = 0; nf < 4; ++nf)
                    acc[mf][nf] = mfma16(af, bf4[nf], acc[mf][nf]);
            }
        }
        __syncthreads();
        if (more) {
            #pragma unroll
            for (int q = 0; q < 4; ++q) { ha[q] = na[q]; hb[q] = nb[q]; }
        }
    }

    #pragma unroll
    for (int mf = 0; mf < 4; ++mf) {
        const int row = m0 + wm * 64 + mf * 16 + lg * 4;
        #pragma unroll
        for (int nf = 0; nf < 4; ++nf) {
            const int col = j0 + wn * 64 + nf * 16 + lr;
            if (col < N_LOCI) {
                #pragma unroll
                for (int rr = 0; rr < 4; ++rr)
                    if (row + rr < 2 * N_ENC)
                        C[(size_t)(row + rr) * N_LOCI + col] = acc[mf][nf][rr];
            }
        }
    }
}

// ---------------------------------------------------------------------------
extern "C" void kernel_launch(void* const* d_in, const int* in_sizes, int n_in,
                              void* d_out, int out_size, void* d_ws, size_t ws_size,
                              hipStream_t stream) {
    const float* X  = (const float*)d_in[0];
    const float* WL = (const float*)d_in[1];
    const float* WR = (const float*)d_in[2];
    float* C = (float*)d_out;

    // workspace (aliased; total 61,603,840 B):
    //   region A [0, 61079552): P f32 [116][200][512] (47.5 MB) while k2/k3
    //                           run, then overwritten by X_hat bf16 [59648][512]
    //   Ah u16 [512][512] at 61079552
    unsigned short* Xh = (unsigned short*)d_ws;
    float* P           = (float*)d_ws;
    unsigned short* Ah = (unsigned short*)((char*)d_ws + (size_t)J_PAD * T_PAD * 2);

    k2_gemm1<<<dim3(8, G1_S, 2), dim3(256), 0, stream>>>(X, WL, WR, P);
    k3_astats<<<dim3(512), dim3(256), 0, stream>>>(P, Ah);
    k0_xnorm<<<dim3(J_PAD / 4), dim3(256), 0, stream>>>(X, Xh);
    k4_gemm2<<<dim3((N_LOCI + 127) / 128, 4), dim3(256), 0, stream>>>(Ah, Xh, C);
}

// Round 6
// 205.939 us; speedup vs baseline: 1.5780x; 1.1128x over previous
//
#include <hip/hip_runtime.h>

typedef __attribute__((ext_vector_type(8))) __bf16 bf16x8;
typedef __attribute__((ext_vector_type(8))) unsigned short u16x8;
typedef __attribute__((ext_vector_type(4))) unsigned short u16x4;
typedef __attribute__((ext_vector_type(4))) float f32x4;

#define N_LOCI   59412
#define T_DIM    500
#define T_PAD    512
#define N_ENC    200
#define KL       29696
#define KR       29716
#define J_PAD    59648
#define G1_S     58      // split-K chunks per compartment (58*512 >= K)

__device__ __forceinline__ unsigned short cvt1(float x) {
    __bf16 h = (__bf16)x;
    return __builtin_bit_cast(unsigned short, h);
}
__device__ __forceinline__ float bf2f(unsigned short h) {
    return __uint_as_float(((unsigned)h) << 16);
}
__device__ __forceinline__ f32x4 mfma16(u16x8 a, u16x8 b, f32x4 c) {
    return __builtin_amdgcn_mfma_f32_16x16x32_bf16(
        __builtin_bit_cast(bf16x8, a), __builtin_bit_cast(bf16x8, b), c, 0, 0, 0);
}

// ---------------------------------------------------------------------------
// K2: bf16 partials P16[g][200][512] of A = W_c @ X_slice (RAW, uncentered),
// plus (mt==0): raw-bf16 Xb[loci][512]. Tile M=64 x N=256, BK=64, 256 thr
// (4 waves, wave 64m x 64n). B staged transposed [n][64] with XOR-swizzle
// key(n) = (((n>>2)^(n>>5))&7)<<3; A staged [m][64] with key(m)=((m>>2)&7)<<3.
// Grid 1024 slot-major: d = slot*128 + g; g<116; slot=(mt*2+nt).
// All 8 slots of chunk g share its X rows -> same XCD (g%8) L2.
// ---------------------------------------------------------------------------
__global__ __launch_bounds__(256) void k2_gemm1(const float* __restrict__ X,
                                                const float* __restrict__ WL,
                                                const float* __restrict__ WR,
                                                unsigned short* __restrict__ P16,
                                                unsigned short* __restrict__ Xb) {
    const int d = blockIdx.x;
    const int g = d & 127;
    if (g >= 2 * G1_S) return;
    const int slot = d >> 7;       // 0..7
    const int mt = slot >> 1;      // 0..3
    const int nt = slot & 1;       // 0..1
    const int sc   = g >> 1;       // 0..57
    const int comp = g & 1;
    const int K      = comp ? KR : KL;
    const float* W   = comp ? WR : WL;
    const int xbase  = comp ? KL : 0;
    const int m0 = mt * 64;
    const int n0 = nt * 256;
    const bool emit = (mt == 0);

    __shared__ unsigned short As[64 * 64];
    __shared__ unsigned short Bs[256 * 64];

    const int t = threadIdx.x, lane = t & 63;
    const int wid = t >> 6;
    const int lr = lane & 15, lg = lane >> 4;

    f32x4 acc[4][4];
    #pragma unroll
    for (int i = 0; i < 4; ++i)
        #pragma unroll
        for (int j = 0; j < 4; ++j) {
            f32x4 z = {0.f, 0.f, 0.f, 0.f};
            acc[i][j] = z;
        }

    const int nsteps = (comp && sc == G1_S - 1) ? 9 : 8;

    // A staging: row am (0..63), 16-k segment ak
    const int am = t >> 2, ak = (t & 3) * 16;
    const int arow = (m0 + am < N_ENC) ? (m0 + am) : (N_ENC - 1);
    const float* wrow = W + (size_t)arow * K;
    const int akeyw = ((am >> 2) & 7) << 3;
    // B staging: k-quad kq (4 rows), col thread tc (cols n0 + g2*128 + tc*8 + j)
    const int kq = t >> 4, tc = t & 15;

    u16x8 ha[2];
    unsigned short hv[4][16];

    auto load_tiles = [&](int st) {
        const int k0 = sc * 512 + st * 64;
        // ---- A: 16 k per thread ----
        {
            const int kb = k0 + ak;
            float av[16];
            if (kb + 15 < K) {
                #pragma unroll
                for (int f = 0; f < 4; ++f) {
                    const float4 v = *(const float4*)(wrow + kb + f * 4);
                    av[f * 4 + 0] = v.x; av[f * 4 + 1] = v.y;
                    av[f * 4 + 2] = v.z; av[f * 4 + 3] = v.w;
                }
            } else {
                #pragma unroll
                for (int j = 0; j < 16; ++j)
                    av[j] = (kb + j < K) ? wrow[kb + j] : 0.0f;
            }
            #pragma unroll
            for (int h2 = 0; h2 < 2; ++h2) {
                u16x8 hh;
                #pragma unroll
                for (int j = 0; j < 8; ++j) hh[j] = cvt1(av[h2 * 8 + j]);
                ha[h2] = hh;
            }
        }
        // ---- B: 4 rows x 16 cols per thread ----
        #pragma unroll
        for (int r = 0; r < 4; ++r) {
            const int krel = k0 + kq * 4 + r;
            const bool kok = krel < K;
            const float* xr = X + (size_t)(xbase + krel) * T_DIM;
            #pragma unroll
            for (int g2 = 0; g2 < 2; ++g2) {
                const int c = n0 + g2 * 128 + tc * 8;
                float xv[8];
                if (kok && c + 7 < T_DIM) {
                    const float4 v0 = *(const float4*)(xr + c);
                    const float4 v1 = *(const float4*)(xr + c + 4);
                    xv[0] = v0.x; xv[1] = v0.y; xv[2] = v0.z; xv[3] = v0.w;
                    xv[4] = v1.x; xv[5] = v1.y; xv[6] = v1.z; xv[7] = v1.w;
                } else {
                    #pragma unroll
                    for (int j = 0; j < 8; ++j)
                        xv[j] = (kok && c + j < T_DIM) ? xr[c + j] : 0.0f;
                }
                #pragma unroll
                for (int j = 0; j < 8; ++j)
                    hv[r][g2 * 8 + j] = cvt1(xv[j]);
            }
        }
    };

    auto write_stage = [&](int st) {
        // A LDS (swizzled, u16x8)
        *(u16x8*)&As[am * 64 + (ak ^ akeyw)]       = ha[0];
        *(u16x8*)&As[am * 64 + ((ak + 8) ^ akeyw)] = ha[1];
        // B LDS transposed (swizzled, u16x4 along k)
        #pragma unroll
        for (int g2 = 0; g2 < 2; ++g2)
            #pragma unroll
            for (int j = 0; j < 8; ++j) {
                const int nl = g2 * 128 + tc * 8 + j;
                const int key = (((nl >> 2) ^ (nl >> 5)) & 7) << 3;
                u16x4 w4 = { hv[0][g2 * 8 + j], hv[1][g2 * 8 + j],
                             hv[2][g2 * 8 + j], hv[3][g2 * 8 + j] };
                *(u16x4*)&Bs[nl * 64 + ((kq * 4) ^ key)] = w4;
            }
        // Xb emission (raw bf16, coalesced u16x8)
        if (emit) {
            const int k0 = sc * 512 + st * 64;
            #pragma unroll
            for (int r = 0; r < 4; ++r) {
                const int krel = k0 + kq * 4 + r;
                if (krel < K) {
                    #pragma unroll
                    for (int g2 = 0; g2 < 2; ++g2) {
                        u16x8 hh;
                        #pragma unroll
                        for (int j = 0; j < 8; ++j) hh[j] = hv[r][g2 * 8 + j];
                        *(u16x8*)&Xb[(size_t)(xbase + krel) * T_PAD + n0 + g2 * 128 + tc * 8] = hh;
                    }
                }
            }
        }
    };

    load_tiles(0);
    for (int st = 0; st < nsteps; ++st) {
        write_stage(st);
        __syncthreads();
        if (st + 1 < nsteps) load_tiles(st + 1);   // reg prefetch (ha/hv already in LDS)
        #pragma unroll
        for (int h = 0; h < 2; ++h) {
            u16x8 af[4], bf[4];
            #pragma unroll
            for (int mf = 0; mf < 4; ++mf) {
                const int m = mf * 16 + lr;
                af[mf] = *(const u16x8*)&As[m * 64 + ((h * 32 + lg * 8) ^ (((m >> 2) & 7) << 3))];
            }
            #pragma unroll
            for (int nf = 0; nf < 4; ++nf) {
                const int nl = wid * 64 + nf * 16 + lr;
                const int key = (((nl >> 2) ^ (nl >> 5)) & 7) << 3;
                bf[nf] = *(const u16x8*)&Bs[nl * 64 + ((h * 32 + lg * 8) ^ key)];
            }
            #pragma unroll
            for (int mf = 0; mf < 4; ++mf)
                #pragma unroll
                for (int nf = 0; nf < 4; ++nf)
                    acc[mf][nf] = mfma16(af[mf], bf[nf], acc[mf][nf]);
        }
        __syncthreads();
    }

    unsigned short* Pb = P16 + (size_t)g * (200 * 512);
    #pragma unroll
    for (int mf = 0; mf < 4; ++mf)
        #pragma unroll
        for (int rr = 0; rr < 4; ++rr) {
            const int m = m0 + mf * 16 + lg * 4 + rr;
            if (m < N_ENC) {
                #pragma unroll
                for (int nf = 0; nf < 4; ++nf) {
                    const int n = n0 + wid * 64 + nf * 16 + lr;
                    Pb[(size_t)m * 512 + n] = cvt1(acc[mf][nf][rr]);
                }
            }
        }
}

// ---------------------------------------------------------------------------
// K3: sum bf16 split-K partials (slice index = s2*2 + comp) -> raw A row;
// store RAW bf16 Ab [512][512] (pad zero) + astat=(mu, 1/||Ac||).
// ---------------------------------------------------------------------------
__global__ __launch_bounds__(256) void k3_astats(const unsigned short* __restrict__ P16,
                                                 unsigned short* __restrict__ Ab,
                                                 float2* __restrict__ astat) {
    const int r = blockIdx.x;   // 0..511
    const int t = threadIdx.x;  // 0..255
    unsigned short* out = Ab + (size_t)r * T_PAD;
    if (r >= 2 * N_ENC) {
        out[t] = 0; out[t + 256] = 0;
        if (t == 0) astat[r] = make_float2(0.0f, 0.0f);
        return;
    }
    const int comp = (r >= N_ENC) ? 1 : 0;
    const int m = r - comp * N_ENC;
    float a1 = 0.0f, a2 = 0.0f;
    for (int s2 = 0; s2 < G1_S; ++s2) {
        const unsigned short* Pb = P16 + ((size_t)(s2 * 2 + comp) * 200 + m) * 512;
        a1 += bf2f(Pb[t]);
        a2 += bf2f(Pb[t + 256]);
    }
    const bool v2ok = (t + 256) < T_DIM;
    const float b2 = v2ok ? a2 : 0.0f;
    float s = a1 + b2;
    float q = a1 * a1 + b2 * b2;
    #pragma unroll
    for (int off = 32; off; off >>= 1) {
        s += __shfl_xor(s, off);
        q += __shfl_xor(q, off);
    }
    __shared__ float ls[4], lq[4];
    if ((t & 63) == 0) { ls[t >> 6] = s; lq[t >> 6] = q; }
    __syncthreads();
    const float S = ls[0] + ls[1] + ls[2] + ls[3];
    const float Q = lq[0] + lq[1] + lq[2] + lq[3];
    const float mean = S * (1.0f / 500.0f);
    const float iv   = rsqrtf(Q - 500.0f * mean * mean);
    out[t] = cvt1(a1);
    out[t + 256] = v2ok ? cvt1(a2) : (unsigned short)0;
    if (t == 0) astat[r] = make_float2(mean, iv);
}

// ---------------------------------------------------------------------------
// K1x: per-locus stats from raw bf16 Xb: xstat = (mu, 1/||xc||). Wave/row.
// ---------------------------------------------------------------------------
__global__ __launch_bounds__(256) void k1_xstat(const unsigned short* __restrict__ Xb,
                                                float2* __restrict__ xstat) {
    const int row  = blockIdx.x * 4 + (threadIdx.x >> 6);
    const int lane = threadIdx.x & 63;
    if (row >= N_LOCI) {
        if (lane == 0 && row < J_PAD) xstat[row] = make_float2(0.0f, 0.0f);
        return;
    }
    const u16x8 v = *(const u16x8*)(Xb + (size_t)row * T_PAD + lane * 8);
    float s = 0.0f, q = 0.0f;
    #pragma unroll
    for (int j = 0; j < 8; ++j) {
        const float f = bf2f(v[j]);   // cols >= 500 are zero
        s += f; q += f * f;
    }
    #pragma unroll
    for (int off = 32; off; off >>= 1) {
        s += __shfl_xor(s, off);
        q += __shfl_xor(q, off);
    }
    if (lane == 0) {
        const float mu = s * (1.0f / 500.0f);
        xstat[row] = make_float2(mu, rsqrtf(q - 500.0f * mu * mu));
    }
}

// ---------------------------------------------------------------------------
// K4: G = Ab @ Xb^T (raw), epilogue C = (G - 500*muA*muX)*invA*invX.
// Tile 128m x 128j, 256 thr, proven swizzled LDS + reg prefetch.
// Grid 1888 decoded XCD-grouped: jt=(d>>5)*8+(d&7), mt=(d>>3)&3.
// ---------------------------------------------------------------------------
__global__ __launch_bounds__(256, 3) void k4_gemm2(const unsigned short* __restrict__ Ab,
                                                   const unsigned short* __restrict__ Xb,
                                                   const float2* __restrict__ astat,
                                                   const float2* __restrict__ xstat,
                                                   float* __restrict__ C) {
    const int d  = blockIdx.x;
    const int jt = (d >> 5) * 8 + (d & 7);
    if (jt >= 465) return;
    const int mt = (d >> 3) & 3;
    const int j0 = jt * 128;
    const int m0 = mt * 128;

    __shared__ unsigned short As[128 * 64];
    __shared__ unsigned short Bs[128 * 64];
    const int t = threadIdx.x, lane = t & 63;
    const int wm = (t >> 6) >> 1, wnn = (t >> 6) & 1;
    const int lg = lane >> 4, lr = lane & 15;

    f32x4 acc[4][4];
    #pragma unroll
    for (int i = 0; i < 4; ++i)
        #pragma unroll
        for (int j = 0; j < 4; ++j) {
            f32x4 z = {0.f, 0.f, 0.f, 0.f};
            acc[i][j] = z;
        }

    const int ar = t >> 1, aseg = t & 1;
    const unsigned short* ag = Ab + (size_t)(m0 + ar) * T_PAD + aseg * 32;
    const unsigned short* bg = Xb + (size_t)(j0 + ar) * T_PAD + aseg * 32;
    const int akey = ((ar >> 2) & 7) << 3;

    u16x8 ha[4], hb[4];
    auto load4 = [&](int k0, u16x8 (&la)[4], u16x8 (&lb)[4]) {
        #pragma unroll
        for (int q = 0; q < 4; ++q) la[q] = *(const u16x8*)(ag + k0 + q * 8);
        #pragma unroll
        for (int q = 0; q < 4; ++q) lb[q] = *(const u16x8*)(bg + k0 + q * 8);
    };
    load4(0, ha, hb);

    for (int st = 0; st < 8; ++st) {
        #pragma unroll
        for (int q = 0; q < 4; ++q) {
            const int off = ar * 64 + ((aseg * 32 + q * 8) ^ akey);
            *(u16x8*)&As[off] = ha[q];
            *(u16x8*)&Bs[off] = hb[q];
        }
        __syncthreads();
        u16x8 na[4], nb[4];
        const bool more = st < 7;
        if (more) load4((st + 1) * 64, na, nb);
        #pragma unroll
        for (int h = 0; h < 2; ++h) {
            u16x8 bf4[4];
            #pragma unroll
            for (int nf = 0; nf < 4; ++nf) {
                const int n = wnn * 64 + nf * 16 + lr;
                bf4[nf] = *(const u16x8*)&Bs[n * 64 + ((h * 32 + lg * 8) ^ (((n >> 2) & 7) << 3))];
            }
            #pragma unroll
            for (int mf = 0; mf < 4; ++mf) {
                const int m = wm * 64 + mf * 16 + lr;
                const u16x8 af = *(const u16x8*)&As[m * 64 + ((h * 32 + lg * 8) ^ (((m >> 2) & 7) << 3))];
                #pragma unroll
                for (int nf = 0; nf < 4; ++nf)
                    acc[mf][nf] = mfma16(af, bf4[nf], acc[mf][nf]);
            }
        }
        __syncthreads();
        if (more) {
            #pragma unroll
            for (int q = 0; q < 4; ++q) { ha[q] = na[q]; hb[q] = nb[q]; }
        }
    }

    #pragma unroll
    for (int mf = 0; mf < 4; ++mf) {
        const int row = m0 + wm * 64 + mf * 16 + lg * 4;
        #pragma unroll
        for (int nf = 0; nf < 4; ++nf) {
            const int col = j0 + wnn * 64 + nf * 16 + lr;
            if (col < N_LOCI) {
                const float2 xs = xstat[col];
                #pragma unroll
                for (int rr = 0; rr < 4; ++rr) {
                    if (row + rr < 2 * N_ENC) {
                        const float2 as = astat[row + rr];
                        C[(size_t)(row + rr) * N_LOCI + col] =
                            (acc[mf][nf][rr] - 500.0f * as.x * xs.x) * as.y * xs.y;
                    }
                }
            }
        }
    }
}

// ---------------------------------------------------------------------------
extern "C" void kernel_launch(void* const* d_in, const int* in_sizes, int n_in,
                              void* d_out, int out_size, void* d_ws, size_t ws_size,
                              hipStream_t stream) {
    const float* X  = (const float*)d_in[0];
    const float* WL = (const float*)d_in[1];
    const float* WR = (const float*)d_in[2];
    float* C = (float*)d_out;

    // workspace (total ~85.8 MB):
    //   Xb    u16 [59648][512]     : 61,079,552 B
    //   P16   u16 [116][200][512]  : 23,756,800 B
    //   Ab    u16 [512][512]       :    524,288 B
    //   astat f32x2 [512]          :      4,096 B
    //   xstat f32x2 [59648]        :    477,184 B
    char* w = (char*)d_ws;
    unsigned short* Xb  = (unsigned short*)w;  w += (size_t)J_PAD * T_PAD * 2;
    unsigned short* P16 = (unsigned short*)w;  w += (size_t)2 * G1_S * 200 * 512 * 2;
    unsigned short* Ab  = (unsigned short*)w;  w += (size_t)512 * 512 * 2;
    float2* astat = (float2*)w;                w += (size_t)512 * 8;
    float2* xstat = (float2*)w;

    k2_gemm1<<<dim3(1024), dim3(256), 0, stream>>>(X, WL, WR, P16, Xb);
    k3_astats<<<dim3(512), dim3(256), 0, stream>>>(P16, Ab, astat);
    k1_xstat<<<dim3(J_PAD / 4), dim3(256), 0, stream>>>(Xb, xstat);
    k4_gemm2<<<dim3(1888), dim3(256), 0, stream>>>(Ab, Xb, astat, xstat, C);
}